// Round 1
// baseline (1028.472 us; speedup 1.0000x reference)
//
#include <hip/hip_runtime.h>

#define NN 256
#define TT 512
#define BB 1024
#define DTC 0.01f

typedef _Float16 half8 __attribute__((ext_vector_type(8)));
typedef float f32x4 __attribute__((ext_vector_type(4)));

// One block = 16 batch rows for all 512 steps. 8 waves x 64 lanes.
// Wave w owns output neurons [32w, 32w+32) as two 16-wide M-tiles.
// GEMM computed transposed: D[m=neuron][n=batchrow] = W_eff^T * s^T.
//   A-operand (W^T) resident in registers, hi/lo fp16 split.
//   B-operand (state^T) in LDS fragments, hi/lo fp16, dynamic pow2 scaling.
__global__ __launch_bounds__(512, 2) void ring_attractor_kernel(
    const float* __restrict__ W, const float* __restrict__ log_scale,
    const float* __restrict__ gain, const float* __restrict__ bias,
    const float* __restrict__ log_tau, const float* __restrict__ vscale_p,
    const float* __restrict__ lscale_p, const float* __restrict__ velocity,
    const float* __restrict__ landmarks, float* __restrict__ out) {
  __shared__ __align__(16) _Float16 fragH[2][4096];  // s_hi frags, 8KB each buf
  __shared__ __align__(16) _Float16 fragL[2][4096];  // s_lo frags
  __shared__ float maxslot[2][8];

  const int tid = threadIdx.x;
  const int w  = tid >> 6;     // wave 0..7
  const int l  = tid & 63;     // lane
  const int g  = l >> 4;       // k-group 0..3
  const int li = l & 15;       // row-within-16 / batch index
  const int br = blockIdx.x * 16 + li;  // this lane's batch row (n-dim)

  const float es  = expf(log_scale[0]);
  const float vs  = vscale_p[0];
  const float lms = lscale_p[0];

  // Per-lane output neurons (D layout): c = 32w + 16nt + 4g + q
  float gain_r[2][4], bias_r[2][4], coef_r[2][4];
#pragma unroll
  for (int nt = 0; nt < 2; ++nt)
#pragma unroll
    for (int q = 0; q < 4; ++q) {
      int c = w * 32 + nt * 16 + g * 4 + q;
      gain_r[nt][q] = gain[c];
      bias_r[nt][q] = bias[c];
      coef_r[nt][q] = DTC / expf(log_tau[c]);
    }

  // Resident A-operand: W_eff^T fragments, hi/lo fp16.
  // A[m][k]: m = lane&15 (+tile base), k = 32ks + 4g + (j&3) + 16(j>>2)
  // value = W_eff[k][m] = es * W[k*256 + m]
  half8 whi[2][8], wlo[2][8];
#pragma unroll
  for (int nt = 0; nt < 2; ++nt)
#pragma unroll
    for (int ks = 0; ks < 8; ++ks) {
      half8 hi, lo;
#pragma unroll
      for (int j = 0; j < 8; ++j) {
        int k = ks * 32 + g * 4 + (j & 3) + ((j >> 2) << 4);
        int m = w * 32 + nt * 16 + li;
        float wv = W[k * NN + m] * es;
        _Float16 h = (_Float16)wv;
        hi[j] = h;
        lo[j] = (_Float16)(wv - (float)h);
      }
      whi[nt][ks] = hi;
      wlo[nt][ks] = lo;
    }

  // Persistent fp32 state in D layout: s_r[nt][q] for (c, br)
  float s_r[2][4];
#pragma unroll
  for (int nt = 0; nt < 2; ++nt)
#pragma unroll
    for (int q = 0; q < 4; ++q) s_r[nt][q] = 0.f;

  // Prologue: zero frags for s_0, zero max, one barrier.
  {
    half8 z;
#pragma unroll
    for (int j = 0; j < 8; ++j) z[j] = (_Float16)0.f;
    const int wbase = ((w * 4 + g) * 16 + li) * 8;
    *reinterpret_cast<half8*>(&fragH[0][wbase]) = z;
    *reinterpret_cast<half8*>(&fragL[0][wbase]) = z;
    if (l == 0) maxslot[0][w] = 0.f;
  }
  float inv_scale = 1.f;
  __syncthreads();

  const int lmc = w * 32 + g * 4;  // landmark col base (valid for w<2)

#pragma unroll 1
  for (int t = 0; t < TT; ++t) {
    const int cur = t & 1, nxt = cur ^ 1;

    // Prefetch external inputs for this step (hidden under MFMA section)
    f32x4 lm0{}, lm1{};
    float v0 = 0.f, v1 = 0.f;
    if (w < 2) {
      const float* p = landmarks + ((size_t)t * BB + br) * 64 + lmc;
      lm0 = *reinterpret_cast<const f32x4*>(p);
      lm1 = *reinterpret_cast<const f32x4*>(p + 16);
    } else if (w < 4) {
      const float* p = velocity + ((size_t)t * BB + br) * 2;
      v0 = p[0];
      v1 = p[1];
    }

    // Block max of |s_t| (written by all waves before last barrier)
    float M;
    {
      const f32x4* mp = reinterpret_cast<const f32x4*>(&maxslot[cur][0]);
      f32x4 a = mp[0], b = mp[1];
      M = fmaxf(fmaxf(fmaxf(a[0], a[1]), fmaxf(a[2], a[3])),
                fmaxf(fmaxf(b[0], b[1]), fmaxf(b[2], b[3])));
    }
    // pow2 scale for quantizing s_{t+1}: target scaled max ~2^10,
    // headroom for per-step growth (bounded ~11x by ||W||_1)
    float scale_n, inv_n;
    {
      unsigned mb = __float_as_uint(M);
      if (mb == 0u) {
        scale_n = 1.f;
        inv_n = 1.f;
      } else {
        int e = 137 - (int)(mb >> 23);
        e = e < -126 ? -126 : (e > 126 ? 126 : e);
        scale_n = __uint_as_float((unsigned)(e + 127) << 23);
        inv_n = __uint_as_float((unsigned)(127 - e) << 23);
      }
    }

    // GEMM: 3 fp16 terms = s_hi*W_hi + s_hi*W_lo + s_lo*W_hi (fp32 acc)
    f32x4 a0h{}, a1h{}, a0l{}, a1l{}, a0c{}, a1c{};
#pragma unroll
    for (int ks = 0; ks < 8; ++ks) {
      const int rb = (ks * 64 + g * 16 + li) * 8;
      half8 bh = *reinterpret_cast<const half8*>(&fragH[cur][rb]);
      half8 bl = *reinterpret_cast<const half8*>(&fragL[cur][rb]);
      a0h = __builtin_amdgcn_mfma_f32_16x16x32_f16(whi[0][ks], bh, a0h, 0, 0, 0);
      a1h = __builtin_amdgcn_mfma_f32_16x16x32_f16(whi[1][ks], bh, a1h, 0, 0, 0);
      a0l = __builtin_amdgcn_mfma_f32_16x16x32_f16(wlo[0][ks], bh, a0l, 0, 0, 0);
      a1l = __builtin_amdgcn_mfma_f32_16x16x32_f16(wlo[1][ks], bh, a1l, 0, 0, 0);
      a0c = __builtin_amdgcn_mfma_f32_16x16x32_f16(whi[0][ks], bl, a0c, 0, 0, 0);
      a1c = __builtin_amdgcn_mfma_f32_16x16x32_f16(whi[1][ks], bl, a1c, 0, 0, 0);
    }

    // Elementwise update (fp32)
    float am = 0.f;
#pragma unroll
    for (int nt = 0; nt < 2; ++nt) {
#pragma unroll
      for (int q = 0; q < 4; ++q) {
        float acc = nt ? (a1h[q] + a1l[q] + a1c[q]) : (a0h[q] + a0l[q] + a0c[q]);
        float ext;
        if (w < 2)
          ext = lms * (nt ? lm1[q] : lm0[q]);
        else if (w == 2)
          ext = vs * v0;
        else if (w == 3)
          ext = vs * v1;
        else
          ext = 0.f;
        float total = acc * inv_scale + ext;
        float rate = fmaxf(gain_r[nt][q] * total + bias_r[nt][q], 0.f);
        float sv = s_r[nt][q];
        sv = sv + coef_r[nt][q] * (rate - sv);
        s_r[nt][q] = sv;
        am = fmaxf(am, fabsf(sv));
      }
    }

    // Wave max -> LDS slot for next step's scale
#pragma unroll
    for (int off = 1; off < 64; off <<= 1) am = fmaxf(am, __shfl_xor(am, off));
    if (l == 0) maxslot[nxt][w] = am;

    // Quantize s_{t+1} hi/lo and write own B-fragment slice (lane-contiguous 16B)
    half8 hb, lb;
#pragma unroll
    for (int j = 0; j < 8; ++j) {
      float sc = s_r[j >> 2][j & 3] * scale_n;
      _Float16 h = (_Float16)sc;
      hb[j] = h;
      lb[j] = (_Float16)(sc - (float)h);
    }
    const int wbase = ((w * 4 + g) * 16 + li) * 8;
    *reinterpret_cast<half8*>(&fragH[nxt][wbase]) = hb;
    *reinterpret_cast<half8*>(&fragL[nxt][wbase]) = lb;
    inv_scale = inv_n;
    __syncthreads();
  }

  // Epilogue: epg output = neurons [0,64) -> waves 0,1
  if (w < 2) {
#pragma unroll
    for (int nt = 0; nt < 2; ++nt) {
      int c0 = w * 32 + nt * 16 + g * 4;
      f32x4 o;
#pragma unroll
      for (int q = 0; q < 4; ++q) o[q] = s_r[nt][q];
      *reinterpret_cast<f32x4*>(out + (size_t)br * 64 + c0) = o;
    }
  }
}

extern "C" void kernel_launch(void* const* d_in, const int* in_sizes, int n_in,
                              void* d_out, int out_size, void* d_ws, size_t ws_size,
                              hipStream_t stream) {
  const float* W         = (const float*)d_in[0];
  const float* log_scale = (const float*)d_in[1];
  const float* gain      = (const float*)d_in[2];
  const float* bias      = (const float*)d_in[3];
  const float* log_tau   = (const float*)d_in[4];
  const float* vscale    = (const float*)d_in[5];
  const float* lscale    = (const float*)d_in[6];
  const float* velocity  = (const float*)d_in[7];
  const float* landmarks = (const float*)d_in[8];
  float* out = (float*)d_out;

  ring_attractor_kernel<<<dim3(BB / 16), dim3(512), 0, stream>>>(
      W, log_scale, gain, bias, log_tau, vscale, lscale, velocity, landmarks, out);
}

// Round 2
// 1009.416 us; speedup vs baseline: 1.0189x; 1.0189x over previous
//
#include <hip/hip_runtime.h>

#define NN 256
#define TT 512
#define BB 1024
#define DTC 0.01f

typedef _Float16 half8 __attribute__((ext_vector_type(8)));
typedef float f32x4 __attribute__((ext_vector_type(4)));

// MFMA with A-operand pinned in AGPRs (forces W residency; gfx950 allows
// AGPR src0 directly). C=0 variant uses inline-constant src2.
__device__ __forceinline__ f32x4 mfma_z(half8 a, half8 b) {
  f32x4 d;
  asm("v_mfma_f32_16x16x32_f16 %0, %1, %2, 0" : "=v"(d) : "a"(a), "v"(b));
  return d;
}
__device__ __forceinline__ void mfma_p(f32x4& c, half8 a, half8 b) {
  asm("v_mfma_f32_16x16x32_f16 %0, %1, %2, %0" : "+v"(c) : "a"(a), "v"(b));
}

// One block = 16 batch rows for all 512 steps. 8 waves x 64 lanes.
// Wave w owns output neurons [32w, 32w+32) as two 16-wide M-tiles.
// GEMM transposed: D[m=neuron][n=batchrow] = W_eff^T * s^T.
// W^T resident in 128 AGPRs (hi/lo fp16); state^T in LDS frags, pow2-scaled.
__global__ __launch_bounds__(512, 2) void ring_attractor_kernel(
    const float* __restrict__ W, const float* __restrict__ log_scale,
    const float* __restrict__ gain, const float* __restrict__ bias,
    const float* __restrict__ log_tau, const float* __restrict__ vscale_p,
    const float* __restrict__ lscale_p, const float* __restrict__ velocity,
    const float* __restrict__ landmarks, float* __restrict__ out) {
  __shared__ __align__(16) _Float16 fragH[2][4096];
  __shared__ __align__(16) _Float16 fragL[2][4096];
  __shared__ float maxslot[2][8];

  const int tid = threadIdx.x;
  const int w  = tid >> 6;
  const int l  = tid & 63;
  const int g  = l >> 4;
  const int li = l & 15;
  const int br = blockIdx.x * 16 + li;

  const float es  = expf(log_scale[0]);
  const float vs  = vscale_p[0];
  const float lms = lscale_p[0];

  float gain_r[2][4], bias_r[2][4], coef_r[2][4];
#pragma unroll
  for (int nt = 0; nt < 2; ++nt)
#pragma unroll
    for (int q = 0; q < 4; ++q) {
      int c = w * 32 + nt * 16 + g * 4 + q;
      gain_r[nt][q] = gain[c];
      bias_r[nt][q] = bias[c];
      coef_r[nt][q] = DTC / expf(log_tau[c]);
    }

  // W_eff^T fragments, hi/lo fp16. A[m][k]: m = lane&15 (+tile), k = 32ks+4g+(j&3)+16(j>>2)
  half8 whi[2][8], wlo[2][8];
#pragma unroll
  for (int nt = 0; nt < 2; ++nt)
#pragma unroll
    for (int ks = 0; ks < 8; ++ks) {
      half8 hi, lo;
#pragma unroll
      for (int j = 0; j < 8; ++j) {
        int k = ks * 32 + g * 4 + (j & 3) + ((j >> 2) << 4);
        int m = w * 32 + nt * 16 + li;
        float wv = W[k * NN + m] * es;
        _Float16 h = (_Float16)wv;
        hi[j] = h;
        lo[j] = (_Float16)(wv - (float)h);
      }
      whi[nt][ks] = hi;
      wlo[nt][ks] = lo;
    }

  float s_r[2][4];
#pragma unroll
  for (int nt = 0; nt < 2; ++nt)
#pragma unroll
    for (int q = 0; q < 4; ++q) s_r[nt][q] = 0.f;

  const int wbase = ((w * 4 + g) * 16 + li) * 8;
  {
    half8 z;
#pragma unroll
    for (int j = 0; j < 8; ++j) z[j] = (_Float16)0.f;
    *reinterpret_cast<half8*>(&fragH[0][wbase]) = z;
    *reinterpret_cast<half8*>(&fragL[0][wbase]) = z;
    if (l == 0) maxslot[0][w] = 0.f;
  }
  float inv_scale = 1.f;
  __syncthreads();

  const int lmc = w * 32 + g * 4;

  // Ext-input double-buffer registers (A = current, B = next), static names.
  f32x4 lmA0{}, lmA1{}, lmB0{}, lmB1{};
  float vA0 = 0.f, vA1 = 0.f, vB0 = 0.f, vB1 = 0.f;
  if (w < 2) {
    const float* p = landmarks + (size_t)br * 64 + lmc;
    lmA0 = *reinterpret_cast<const f32x4*>(p);
    lmA1 = *reinterpret_cast<const f32x4*>(p + 16);
  } else if (w < 4) {
    const float* p = velocity + (size_t)br * 2;
    vA0 = p[0];
    vA1 = p[1];
  }

#define STEP(T, CUR, NXT, LM0, LM1, V0, V1, PLM0, PLM1, PV0, PV1)              \
  {                                                                            \
    float M;                                                                   \
    {                                                                          \
      const f32x4* mp = reinterpret_cast<const f32x4*>(&maxslot[CUR][0]);      \
      f32x4 ma = mp[0], mb = mp[1];                                            \
      M = fmaxf(fmaxf(fmaxf(ma[0], ma[1]), fmaxf(ma[2], ma[3])),               \
                fmaxf(fmaxf(mb[0], mb[1]), fmaxf(mb[2], mb[3])));              \
    }                                                                          \
    float scale_n, inv_n;                                                      \
    {                                                                          \
      unsigned mbts = __float_as_uint(M);                                      \
      if (mbts == 0u) {                                                        \
        scale_n = 1.f;                                                         \
        inv_n = 1.f;                                                           \
      } else {                                                                 \
        int e = 137 - (int)(mbts >> 23);                                       \
        e = e < -126 ? -126 : (e > 126 ? 126 : e);                             \
        scale_n = __uint_as_float((unsigned)(e + 127) << 23);                  \
        inv_n = __uint_as_float((unsigned)(127 - e) << 23);                    \
      }                                                                        \
    }                                                                          \
    {                                                                          \
      const int tn = (T) + 1 < TT ? (T) + 1 : TT - 1;                          \
      if (w < 2) {                                                             \
        const float* p = landmarks + ((size_t)tn * BB + br) * 64 + lmc;        \
        PLM0 = *reinterpret_cast<const f32x4*>(p);                             \
        PLM1 = *reinterpret_cast<const f32x4*>(p + 16);                        \
      } else if (w < 4) {                                                      \
        const float* p = velocity + ((size_t)tn * BB + br) * 2;                \
        PV0 = p[0];                                                            \
        PV1 = p[1];                                                            \
      }                                                                        \
    }                                                                          \
    f32x4 a0h, a1h, a0l, a1l, a0c, a1c;                                        \
    _Pragma("unroll")                                                          \
    for (int ks = 0; ks < 8; ++ks) {                                           \
      const int rb = (ks * 64 + g * 16 + li) * 8;                              \
      half8 bh = *reinterpret_cast<const half8*>(&fragH[CUR][rb]);             \
      half8 bl = *reinterpret_cast<const half8*>(&fragL[CUR][rb]);             \
      if (ks == 0) {                                                           \
        a0h = mfma_z(whi[0][0], bh);                                           \
        a1h = mfma_z(whi[1][0], bh);                                           \
        a0l = mfma_z(wlo[0][0], bh);                                           \
        a1l = mfma_z(wlo[1][0], bh);                                           \
        a0c = mfma_z(whi[0][0], bl);                                           \
        a1c = mfma_z(whi[1][0], bl);                                           \
      } else {                                                                 \
        mfma_p(a0h, whi[0][ks], bh);                                           \
        mfma_p(a1h, whi[1][ks], bh);                                           \
        mfma_p(a0l, wlo[0][ks], bh);                                           \
        mfma_p(a1l, wlo[1][ks], bh);                                           \
        mfma_p(a0c, whi[0][ks], bl);                                           \
        mfma_p(a1c, whi[1][ks], bl);                                           \
      }                                                                        \
    }                                                                          \
    asm volatile("s_nop 7\n\ts_nop 7"                                          \
                 : "+v"(a0h), "+v"(a1h), "+v"(a0l), "+v"(a1l), "+v"(a0c),      \
                   "+v"(a1c));                                                 \
    float am = 0.f;                                                            \
    _Pragma("unroll")                                                          \
    for (int nt = 0; nt < 2; ++nt) {                                           \
      _Pragma("unroll")                                                        \
      for (int q = 0; q < 4; ++q) {                                            \
        float acc = nt ? (a1h[q] + a1l[q] + a1c[q])                            \
                       : (a0h[q] + a0l[q] + a0c[q]);                           \
        float ext;                                                             \
        if (w < 2)                                                             \
          ext = lms * (nt ? LM1[q] : LM0[q]);                                  \
        else if (w == 2)                                                       \
          ext = vs * V0;                                                       \
        else if (w == 3)                                                       \
          ext = vs * V1;                                                       \
        else                                                                   \
          ext = 0.f;                                                           \
        float total = acc * inv_scale + ext;                                   \
        float rate = fmaxf(gain_r[nt][q] * total + bias_r[nt][q], 0.f);        \
        float sv = s_r[nt][q];                                                 \
        sv = sv + coef_r[nt][q] * (rate - sv);                                 \
        s_r[nt][q] = sv;                                                       \
        am = fmaxf(am, fabsf(sv));                                             \
      }                                                                        \
    }                                                                          \
    _Pragma("unroll")                                                          \
    for (int off = 1; off < 64; off <<= 1)                                     \
      am = fmaxf(am, __shfl_xor(am, off));                                     \
    if (l == 0) maxslot[NXT][w] = am;                                          \
    half8 hbq, lbq;                                                            \
    _Pragma("unroll")                                                          \
    for (int j = 0; j < 8; ++j) {                                              \
      float sc = s_r[j >> 2][j & 3] * scale_n;                                 \
      _Float16 hq = (_Float16)sc;                                              \
      hbq[j] = hq;                                                             \
      lbq[j] = (_Float16)(sc - (float)hq);                                     \
    }                                                                          \
    *reinterpret_cast<half8*>(&fragH[NXT][wbase]) = hbq;                       \
    *reinterpret_cast<half8*>(&fragL[NXT][wbase]) = lbq;                       \
    inv_scale = inv_n;                                                         \
    __syncthreads();                                                           \
  }

#pragma unroll 1
  for (int t = 0; t < TT; t += 2) {
    STEP(t, 0, 1, lmA0, lmA1, vA0, vA1, lmB0, lmB1, vB0, vB1)
    STEP(t + 1, 1, 0, lmB0, lmB1, vB0, vB1, lmA0, lmA1, vA0, vA1)
  }
#undef STEP

  // Epilogue: epg output = neurons [0,64) -> waves 0,1
  if (w < 2) {
#pragma unroll
    for (int nt = 0; nt < 2; ++nt) {
      int c0 = w * 32 + nt * 16 + g * 4;
      f32x4 o;
#pragma unroll
      for (int q = 0; q < 4; ++q) o[q] = s_r[nt][q];
      *reinterpret_cast<f32x4*>(out + (size_t)br * 64 + c0) = o;
    }
  }
}

extern "C" void kernel_launch(void* const* d_in, const int* in_sizes, int n_in,
                              void* d_out, int out_size, void* d_ws, size_t ws_size,
                              hipStream_t stream) {
  const float* W         = (const float*)d_in[0];
  const float* log_scale = (const float*)d_in[1];
  const float* gain      = (const float*)d_in[2];
  const float* bias      = (const float*)d_in[3];
  const float* log_tau   = (const float*)d_in[4];
  const float* vscale    = (const float*)d_in[5];
  const float* lscale    = (const float*)d_in[6];
  const float* velocity  = (const float*)d_in[7];
  const float* landmarks = (const float*)d_in[8];
  float* out = (float*)d_out;

  ring_attractor_kernel<<<dim3(BB / 16), dim3(512), 0, stream>>>(
      W, log_scale, gain, bias, log_tau, vscale, lscale, velocity, landmarks, out);
}

// Round 3
// 905.861 us; speedup vs baseline: 1.1354x; 1.1143x over previous
//
#include <hip/hip_runtime.h>

#define NN 256
#define TT 512
#define BB 1024
#define DTC 0.01f

typedef _Float16 half8 __attribute__((ext_vector_type(8)));
typedef float f32x4 __attribute__((ext_vector_type(4)));

// MFMA with A pinned in AGPRs (W stays resident for the whole kernel).
__device__ __forceinline__ f32x4 mfma_z(half8 a, half8 b) {
  f32x4 d;
  asm("v_mfma_f32_16x16x32_f16 %0, %1, %2, 0" : "=v"(d) : "a"(a), "v"(b));
  return d;
}
__device__ __forceinline__ void mfma_p(f32x4& c, half8 a, half8 b) {
  asm("v_mfma_f32_16x16x32_f16 %0, %1, %2, %0" : "+v"(c) : "a"(a), "v"(b));
}

// max with lane rotated-by-CTRL within the 16-lane DPP row (VALU pipe, no LDS)
template <int CTRL>
__device__ __forceinline__ float rormax(float x) {
  int yi = __builtin_amdgcn_update_dpp(0, __float_as_int(x), CTRL, 0xf, 0xf, false);
  return fmaxf(x, __int_as_float(yi));
}

// One block = 16 batch rows for all 512 steps. 8 waves x 64 lanes.
// Wave w owns output neurons [32w,32w+32); GEMM transposed:
// D[m=neuron][n=batchrow] = W_eff^T * s^T; W^T in 128 AGPRs (hi/lo fp16);
// state^T in LDS frags (hi/lo fp16), 2-step-pipelined pow2 scaling.
__global__ __launch_bounds__(512, 2) void ring_attractor_kernel(
    const float* __restrict__ W, const float* __restrict__ log_scale,
    const float* __restrict__ gain, const float* __restrict__ bias,
    const float* __restrict__ log_tau, const float* __restrict__ vscale_p,
    const float* __restrict__ lscale_p, const float* __restrict__ velocity,
    const float* __restrict__ landmarks, float* __restrict__ out) {
  __shared__ __align__(16) _Float16 fragH[2][4096];
  __shared__ __align__(16) _Float16 fragL[2][4096];
  __shared__ __align__(16) float maxslot[2][8];

  const int tid = threadIdx.x;
  const int w  = tid >> 6;
  const int l  = tid & 63;
  const int g  = l >> 4;
  const int li = l & 15;
  const int br = blockIdx.x * 16 + li;

  const float es  = expf(log_scale[0]);
  const float vs  = vscale_p[0];
  const float lms = lscale_p[0];

  float gain_r[2][4], bias_r[2][4], coef_r[2][4];
#pragma unroll
  for (int nt = 0; nt < 2; ++nt)
#pragma unroll
    for (int q = 0; q < 4; ++q) {
      int c = w * 32 + nt * 16 + g * 4 + q;
      gain_r[nt][q] = gain[c];
      bias_r[nt][q] = bias[c];
      coef_r[nt][q] = DTC / expf(log_tau[c]);
    }

  // Resident W_eff^T hi/lo fragments. A[m][k]: m=lane&15(+tile), k=32ks+4g+(j&3)+16(j>>2)
  half8 whi[2][8], wlo[2][8];
#pragma unroll
  for (int nt = 0; nt < 2; ++nt)
#pragma unroll
    for (int ks = 0; ks < 8; ++ks) {
      half8 hi, lo;
#pragma unroll
      for (int j = 0; j < 8; ++j) {
        int k = ks * 32 + g * 4 + (j & 3) + ((j >> 2) << 4);
        int m = w * 32 + nt * 16 + li;
        float wv = W[k * NN + m] * es;
        _Float16 h = (_Float16)wv;
        hi[j] = h;
        lo[j] = (_Float16)(wv - (float)h);
      }
      whi[nt][ks] = hi;
      wlo[nt][ks] = lo;
    }

  float s_r[2][4];
#pragma unroll
  for (int nt = 0; nt < 2; ++nt)
#pragma unroll
    for (int q = 0; q < 4; ++q) s_r[nt][q] = 0.f;

  const int wbase = ((w * 4 + g) * 16 + li) * 8;
  {
    half8 z;
#pragma unroll
    for (int j = 0; j < 8; ++j) z[j] = (_Float16)0.f;
    *reinterpret_cast<half8*>(&fragH[0][wbase]) = z;
    *reinterpret_cast<half8*>(&fragL[0][wbase]) = z;
    if (tid < 16) maxslot[tid >> 3][tid & 7] = 0.f;
  }
  float inv_scale = 1.f;  // scale applied to s_0 (zeros)
  float amPrev = 0.f;     // per-lane max|s_{t+1}|, reduced at top of next step
  const int lmc = w * 32 + g * 4;
  size_t lmoff = (size_t)br * 64 + lmc;  // landmarks elem offset for t=0
  size_t voff  = (size_t)br * 2;         // velocity elem offset for t=0
  __syncthreads();

  // Step T: reads frag[T&1] + maxslot[(T&1)^1] (=M_{T-1}); writes frag[(T&1)^1]
  // + maxslot[T&1] (=M_T, reduced from previous step's amPrev, off critical path).
#define STEP(T, CUR)                                                           \
  {                                                                            \
    /* (1) spill: reduce prev step's am -> maxslot[CUR]; hidden under MFMA */  \
    {                                                                          \
      float r = amPrev;                                                        \
      r = rormax<0x121>(r); /* row_ror:1 */                                    \
      r = rormax<0x122>(r); /* row_ror:2 */                                    \
      r = rormax<0x124>(r); /* row_ror:4 */                                    \
      r = rormax<0x128>(r); /* row_ror:8 */                                    \
      r = fmaxf(r, __shfl_xor(r, 16));                                         \
      r = fmaxf(r, __shfl_xor(r, 32));                                         \
      if (l == 0) maxslot[CUR][w] = r;                                         \
    }                                                                          \
    /* (2) issue M_{T-1} read early */                                         \
    float M;                                                                   \
    {                                                                          \
      const f32x4* mp = reinterpret_cast<const f32x4*>(&maxslot[CUR ^ 1][0]);  \
      f32x4 ma = mp[0], mb = mp[1];                                            \
      M = fmaxf(fmaxf(fmaxf(ma[0], ma[1]), fmaxf(ma[2], ma[3])),               \
                fmaxf(fmaxf(mb[0], mb[1]), fmaxf(mb[2], mb[3])));              \
    }                                                                          \
    /* (3) ext inputs for this step, issued at top (latency under MFMA) */     \
    f32x4 lm0{}, lm1{};                                                        \
    float v0 = 0.f, v1 = 0.f;                                                  \
    if (w < 2) {                                                               \
      const float* p = landmarks + lmoff;                                      \
      lm0 = *reinterpret_cast<const f32x4*>(p);                                \
      lm1 = *reinterpret_cast<const f32x4*>(p + 16);                           \
    } else if (w < 4) {                                                        \
      const float* p = velocity + voff;                                        \
      v0 = p[0];                                                               \
      v1 = p[1];                                                               \
    }                                                                          \
    lmoff += (size_t)BB * 64;                                                  \
    voff += (size_t)BB * 2;                                                    \
    /* (4) GEMM: 6 chains, W in AGPRs, state frags from LDS */                 \
    f32x4 a0h, a1h, a0l, a1l, a0c, a1c;                                        \
    _Pragma("unroll")                                                          \
    for (int ks = 0; ks < 8; ++ks) {                                           \
      const int rb = (ks * 64 + g * 16 + li) * 8;                              \
      half8 bh = *reinterpret_cast<const half8*>(&fragH[CUR][rb]);             \
      half8 bl = *reinterpret_cast<const half8*>(&fragL[CUR][rb]);             \
      if (ks == 0) {                                                           \
        a0h = mfma_z(whi[0][0], bh);                                           \
        a1h = mfma_z(whi[1][0], bh);                                           \
        a0l = mfma_z(wlo[0][0], bh);                                           \
        a1l = mfma_z(wlo[1][0], bh);                                           \
        a0c = mfma_z(whi[0][0], bl);                                           \
        a1c = mfma_z(whi[1][0], bl);                                           \
      } else {                                                                 \
        mfma_p(a0h, whi[0][ks], bh);                                           \
        mfma_p(a1h, whi[1][ks], bh);                                           \
        mfma_p(a0l, wlo[0][ks], bh);                                           \
        mfma_p(a1l, wlo[1][ks], bh);                                           \
        mfma_p(a0c, whi[0][ks], bl);                                           \
        mfma_p(a1c, whi[1][ks], bl);                                           \
      }                                                                        \
    }                                                                          \
    asm volatile("s_nop 7\n\ts_nop 7"                                          \
                 : "+v"(a0h), "+v"(a1h), "+v"(a0l), "+v"(a1l), "+v"(a0c),      \
                   "+v"(a1c));                                                 \
    /* (5) branch-free 2-step-piped scale: target scaled max 2^7, e<=9 */      \
    float scale_n, inv_n;                                                      \
    {                                                                          \
      int e = 134 - (int)(__float_as_uint(M) >> 23);                           \
      e = e > 9 ? 9 : e;                                                       \
      scale_n = __int_as_float((e + 127) << 23);                               \
      inv_n = __int_as_float((127 - e) << 23);                                 \
    }                                                                          \
    /* (6) elementwise update + per-lane max */                                \
    float am = 0.f;                                                            \
    _Pragma("unroll")                                                          \
    for (int nt = 0; nt < 2; ++nt) {                                           \
      _Pragma("unroll")                                                        \
      for (int q = 0; q < 4; ++q) {                                            \
        float acc = nt ? (a1h[q] + a1l[q] + a1c[q])                            \
                       : (a0h[q] + a0l[q] + a0c[q]);                           \
        float ext;                                                             \
        if (w < 2)                                                             \
          ext = lms * (nt ? lm1[q] : lm0[q]);                                  \
        else if (w == 2)                                                       \
          ext = vs * v0;                                                       \
        else if (w == 3)                                                       \
          ext = vs * v1;                                                       \
        else                                                                   \
          ext = 0.f;                                                           \
        float tot = __builtin_fmaf(acc, inv_scale, ext);                       \
        float rate = fmaxf(__builtin_fmaf(gain_r[nt][q], tot, bias_r[nt][q]),  \
                           0.f);                                               \
        float sv = s_r[nt][q];                                                 \
        sv = __builtin_fmaf(coef_r[nt][q], rate - sv, sv);                     \
        s_r[nt][q] = sv;                                                       \
        am = fmaxf(am, fabsf(sv));                                             \
      }                                                                        \
    }                                                                          \
    amPrev = am;                                                               \
    /* (7) quantize s_{T+1} hi/lo, write next frags */                         \
    half8 hbq, lbq;                                                            \
    _Pragma("unroll")                                                          \
    for (int j = 0; j < 8; ++j) {                                              \
      float sc = s_r[j >> 2][j & 3] * scale_n;                                 \
      _Float16 hq = (_Float16)sc;                                              \
      hbq[j] = hq;                                                             \
      lbq[j] = (_Float16)(sc - (float)hq);                                     \
    }                                                                          \
    *reinterpret_cast<half8*>(&fragH[CUR ^ 1][wbase]) = hbq;                   \
    *reinterpret_cast<half8*>(&fragL[CUR ^ 1][wbase]) = lbq;                   \
    inv_scale = inv_n;                                                         \
    __syncthreads();                                                           \
  }

#pragma unroll 1
  for (int t = 0; t < TT; t += 2) {
    STEP(t, 0)
    STEP(t + 1, 1)
  }
#undef STEP

  // Epilogue: epg output = neurons [0,64) -> waves 0,1
  if (w < 2) {
#pragma unroll
    for (int nt = 0; nt < 2; ++nt) {
      int c0 = w * 32 + nt * 16 + g * 4;
      f32x4 o;
#pragma unroll
      for (int q = 0; q < 4; ++q) o[q] = s_r[nt][q];
      *reinterpret_cast<f32x4*>(out + (size_t)br * 64 + c0) = o;
    }
  }
}

extern "C" void kernel_launch(void* const* d_in, const int* in_sizes, int n_in,
                              void* d_out, int out_size, void* d_ws, size_t ws_size,
                              hipStream_t stream) {
  const float* W         = (const float*)d_in[0];
  const float* log_scale = (const float*)d_in[1];
  const float* gain      = (const float*)d_in[2];
  const float* bias      = (const float*)d_in[3];
  const float* log_tau   = (const float*)d_in[4];
  const float* vscale    = (const float*)d_in[5];
  const float* lscale    = (const float*)d_in[6];
  const float* velocity  = (const float*)d_in[7];
  const float* landmarks = (const float*)d_in[8];
  float* out = (float*)d_out;

  ring_attractor_kernel<<<dim3(BB / 16), dim3(512), 0, stream>>>(
      W, log_scale, gain, bias, log_tau, vscale, lscale, velocity, landmarks, out);
}

// Round 4
// 691.901 us; speedup vs baseline: 1.4864x; 1.3092x over previous
//
#include <hip/hip_runtime.h>

#define NN 256
#define TT 512
#define BB 1024
#define DTC 0.01f

typedef _Float16 half8 __attribute__((ext_vector_type(8)));
typedef float f32x4 __attribute__((ext_vector_type(4)));

// MFMA with A pinned in AGPRs (W resident for the whole kernel).
__device__ __forceinline__ f32x4 mfma_z(half8 a, half8 b) {
  f32x4 d;
  asm("v_mfma_f32_16x16x32_f16 %0, %1, %2, 0" : "=v"(d) : "a"(a), "v"(b));
  return d;
}
__device__ __forceinline__ void mfma_p(f32x4& c, half8 a, half8 b) {
  asm("v_mfma_f32_16x16x32_f16 %0, %1, %2, %0" : "+v"(c) : "a"(a), "v"(b));
}

// max with lane rotated-by-CTRL within the 16-lane DPP row (VALU pipe, no LDS)
template <int CTRL>
__device__ __forceinline__ float rormax(float x) {
  int yi = __builtin_amdgcn_update_dpp(0, __float_as_int(x), CTRL, 0xf, 0xf, false);
  return fmaxf(x, __int_as_float(yi));
}

// One block = 16 batch rows, 4 waves. Wave w owns 64 output neurons
// [64w, 64w+64) = 4 A-tiles, so each LDS B-frag read feeds 4 tiles
// (12 MFMAs) instead of 2 — halves LDS traffic vs the 8-wave version.
// GEMM transposed: D[m=neuron][n=batchrow] = W_eff^T * s^T.
// W^T hi/lo fp16 in 256 AGPRs; state^T in LDS frags, 2-step-piped pow2 scale.
__global__ __launch_bounds__(256, 1) void ring_attractor_kernel(
    const float* __restrict__ W, const float* __restrict__ log_scale,
    const float* __restrict__ gain, const float* __restrict__ bias,
    const float* __restrict__ log_tau, const float* __restrict__ vscale_p,
    const float* __restrict__ lscale_p, const float* __restrict__ velocity,
    const float* __restrict__ landmarks, float* __restrict__ out) {
  __shared__ __align__(16) _Float16 fragH[2][4096];
  __shared__ __align__(16) _Float16 fragL[2][4096];
  __shared__ __align__(16) float maxslot[2][4];

  const int tid = threadIdx.x;
  const int w  = tid >> 6;   // 0..3
  const int l  = tid & 63;
  const int g  = l >> 4;
  const int li = l & 15;
  const int br = blockIdx.x * 16 + li;

  const float es  = expf(log_scale[0]);
  const float vs  = vscale_p[0];
  const float lms = lscale_p[0];

  float gain_r[4][4], bias_r[4][4], coef_r[4][4];
#pragma unroll
  for (int nt = 0; nt < 4; ++nt)
#pragma unroll
    for (int q = 0; q < 4; ++q) {
      int c = w * 64 + nt * 16 + g * 4 + q;
      gain_r[nt][q] = gain[c];
      bias_r[nt][q] = bias[c];
      coef_r[nt][q] = DTC / expf(log_tau[c]);
    }

  // Resident W_eff^T hi/lo. A[m][k]: m = w*64+nt*16+li, k = 32ks+4g+(j&3)+16(j>>2)
  half8 whi[4][8], wlo[4][8];
#pragma unroll
  for (int nt = 0; nt < 4; ++nt)
#pragma unroll
    for (int ks = 0; ks < 8; ++ks) {
      half8 hi, lo;
#pragma unroll
      for (int j = 0; j < 8; ++j) {
        int k = ks * 32 + g * 4 + (j & 3) + ((j >> 2) << 4);
        int m = w * 64 + nt * 16 + li;
        float wv = W[k * NN + m] * es;
        _Float16 h = (_Float16)wv;
        hi[j] = h;
        lo[j] = (_Float16)(wv - (float)h);
      }
      whi[nt][ks] = hi;
      wlo[nt][ks] = lo;
    }

  float s_r[4][4];
#pragma unroll
  for (int nt = 0; nt < 4; ++nt)
#pragma unroll
    for (int q = 0; q < 4; ++q) s_r[nt][q] = 0.f;

  // Each lane owns 2 frag slots per buffer (k-slices ks = 2w, 2w+1)
  const int wb0 = ((w * 2 + 0) * 64 + g * 16 + li) * 8;
  const int wb1 = ((w * 2 + 1) * 64 + g * 16 + li) * 8;
  {
    half8 z;
#pragma unroll
    for (int j = 0; j < 8; ++j) z[j] = (_Float16)0.f;
    *reinterpret_cast<half8*>(&fragH[0][wb0]) = z;
    *reinterpret_cast<half8*>(&fragH[0][wb1]) = z;
    *reinterpret_cast<half8*>(&fragL[0][wb0]) = z;
    *reinterpret_cast<half8*>(&fragL[0][wb1]) = z;
    if (tid < 8) maxslot[tid >> 2][tid & 3] = 0.f;
  }
  float inv_scale = 1.f;
  float amPrev = 0.f;

  // Ext double-buffer: wave0 = 16 landmark floats; wave1 = v0,v1 in E0[0],E0[1]
  f32x4 eA0{}, eA1{}, eA2{}, eA3{}, eB0{}, eB1{}, eB2{}, eB3{};
  if (w == 0) {
    const float* p = landmarks + (size_t)br * 64 + g * 4;
    eA0 = *reinterpret_cast<const f32x4*>(p);
    eA1 = *reinterpret_cast<const f32x4*>(p + 16);
    eA2 = *reinterpret_cast<const f32x4*>(p + 32);
    eA3 = *reinterpret_cast<const f32x4*>(p + 48);
  } else if (w == 1) {
    const float* p = velocity + (size_t)br * 2;
    eA0[0] = p[0];
    eA0[1] = p[1];
  }
  __syncthreads();

#define STEP(T, CUR, E0, E1, E2, E3, P0, P1, P2, P3)                           \
  {                                                                            \
    /* (1) reduce prev step's per-lane max -> maxslot[CUR] (off crit path) */  \
    {                                                                          \
      float r = amPrev;                                                        \
      r = rormax<0x121>(r);                                                    \
      r = rormax<0x122>(r);                                                    \
      r = rormax<0x124>(r);                                                    \
      r = rormax<0x128>(r);                                                    \
      r = fmaxf(r, __shfl_xor(r, 16));                                         \
      r = fmaxf(r, __shfl_xor(r, 32));                                         \
      if (l == 0) maxslot[CUR][w] = r;                                         \
    }                                                                          \
    /* (2) M_{T-1} from other buffer (barrier-protected) */                    \
    float M;                                                                   \
    {                                                                          \
      f32x4 mv = *reinterpret_cast<const f32x4*>(&maxslot[CUR ^ 1][0]);        \
      M = fmaxf(fmaxf(mv[0], mv[1]), fmaxf(mv[2], mv[3]));                     \
    }                                                                          \
    /* (3) prefetch ext inputs for step T+1 */                                 \
    {                                                                          \
      const int tn = (T) + 1 < TT ? (T) + 1 : TT - 1;                          \
      if (w == 0) {                                                            \
        const float* p = landmarks + ((size_t)tn * BB + br) * 64 + g * 4;      \
        P0 = *reinterpret_cast<const f32x4*>(p);                               \
        P1 = *reinterpret_cast<const f32x4*>(p + 16);                          \
        P2 = *reinterpret_cast<const f32x4*>(p + 32);                          \
        P3 = *reinterpret_cast<const f32x4*>(p + 48);                          \
      } else if (w == 1) {                                                     \
        const float* p = velocity + ((size_t)tn * BB + br) * 2;                \
        P0[0] = p[0];                                                          \
        P0[1] = p[1];                                                          \
      }                                                                        \
    }                                                                          \
    /* (4) GEMM: 12 chains (4 tiles x {hh, lh, hl}), W in AGPRs */             \
    f32x4 a0h, a1h, a2h, a3h, a0l, a1l, a2l, a3l, a0c, a1c, a2c, a3c;          \
    _Pragma("unroll")                                                          \
    for (int ks = 0; ks < 8; ++ks) {                                           \
      const int rb = (ks * 64 + g * 16 + li) * 8;                              \
      half8 bh = *reinterpret_cast<const half8*>(&fragH[CUR][rb]);             \
      half8 bl = *reinterpret_cast<const half8*>(&fragL[CUR][rb]);             \
      if (ks == 0) {                                                           \
        a0h = mfma_z(whi[0][0], bh);                                           \
        a1h = mfma_z(whi[1][0], bh);                                           \
        a2h = mfma_z(whi[2][0], bh);                                           \
        a3h = mfma_z(whi[3][0], bh);                                           \
        a0l = mfma_z(wlo[0][0], bh);                                           \
        a1l = mfma_z(wlo[1][0], bh);                                           \
        a2l = mfma_z(wlo[2][0], bh);                                           \
        a3l = mfma_z(wlo[3][0], bh);                                           \
        a0c = mfma_z(whi[0][0], bl);                                           \
        a1c = mfma_z(whi[1][0], bl);                                           \
        a2c = mfma_z(whi[2][0], bl);                                           \
        a3c = mfma_z(whi[3][0], bl);                                           \
      } else {                                                                 \
        mfma_p(a0h, whi[0][ks], bh);                                           \
        mfma_p(a1h, whi[1][ks], bh);                                           \
        mfma_p(a2h, whi[2][ks], bh);                                           \
        mfma_p(a3h, whi[3][ks], bh);                                           \
        mfma_p(a0l, wlo[0][ks], bh);                                           \
        mfma_p(a1l, wlo[1][ks], bh);                                           \
        mfma_p(a2l, wlo[2][ks], bh);                                           \
        mfma_p(a3l, wlo[3][ks], bh);                                           \
        mfma_p(a0c, whi[0][ks], bl);                                           \
        mfma_p(a1c, whi[1][ks], bl);                                           \
        mfma_p(a2c, whi[2][ks], bl);                                           \
        mfma_p(a3c, whi[3][ks], bl);                                           \
      }                                                                        \
    }                                                                          \
    asm volatile("s_nop 7\n\ts_nop 7"                                          \
                 : "+v"(a0h), "+v"(a1h), "+v"(a2h), "+v"(a3h), "+v"(a0l),      \
                   "+v"(a1l), "+v"(a2l), "+v"(a3l), "+v"(a0c), "+v"(a1c),      \
                   "+v"(a2c), "+v"(a3c));                                      \
    /* (5) branch-free 2-step-piped scale: target scaled max 2^7, e<=9 */      \
    float scale_n, inv_n;                                                      \
    {                                                                          \
      int e = 134 - (int)(__float_as_uint(M) >> 23);                           \
      e = e > 9 ? 9 : e;                                                       \
      scale_n = __int_as_float((e + 127) << 23);                               \
      inv_n = __int_as_float((127 - e) << 23);                                 \
    }                                                                          \
    /* (6) elementwise update + per-lane max */                                \
    float am = 0.f;                                                            \
    _Pragma("unroll")                                                          \
    for (int nt = 0; nt < 4; ++nt) {                                           \
      f32x4 av = (nt == 0) ? (a0h + a0l + a0c)                                 \
               : (nt == 1) ? (a1h + a1l + a1c)                                 \
               : (nt == 2) ? (a2h + a2l + a2c)                                 \
                           : (a3h + a3l + a3c);                                \
      _Pragma("unroll")                                                        \
      for (int q = 0; q < 4; ++q) {                                            \
        float ext;                                                             \
        if (w == 0) {                                                          \
          f32x4 ev = (nt == 0) ? E0 : (nt == 1) ? E1 : (nt == 2) ? E2 : E3;    \
          ext = lms * ev[q];                                                   \
        } else if (w == 1) {                                                   \
          ext = vs * ((nt < 2) ? E0[0] : E0[1]);                               \
        } else {                                                               \
          ext = 0.f;                                                           \
        }                                                                      \
        float tot = __builtin_fmaf(av[q], inv_scale, ext);                     \
        float rate = fmaxf(__builtin_fmaf(gain_r[nt][q], tot, bias_r[nt][q]),  \
                           0.f);                                               \
        float sv = s_r[nt][q];                                                 \
        sv = __builtin_fmaf(coef_r[nt][q], rate - sv, sv);                     \
        s_r[nt][q] = sv;                                                       \
        am = fmaxf(am, fabsf(sv));                                             \
      }                                                                        \
    }                                                                          \
    amPrev = am;                                                               \
    /* (7) quantize s_{T+1}, write both k-slice slots of next frags */         \
    half8 h0, h1, l0, l1;                                                      \
    _Pragma("unroll")                                                          \
    for (int j = 0; j < 8; ++j) {                                              \
      float sc0 = s_r[j >> 2][j & 3] * scale_n;                                \
      float sc1 = s_r[2 + (j >> 2)][j & 3] * scale_n;                          \
      _Float16 q0 = (_Float16)sc0;                                             \
      _Float16 q1 = (_Float16)sc1;                                             \
      h0[j] = q0;                                                              \
      l0[j] = (_Float16)(sc0 - (float)q0);                                     \
      h1[j] = q1;                                                              \
      l1[j] = (_Float16)(sc1 - (float)q1);                                     \
    }                                                                          \
    *reinterpret_cast<half8*>(&fragH[CUR ^ 1][wb0]) = h0;                      \
    *reinterpret_cast<half8*>(&fragH[CUR ^ 1][wb1]) = h1;                      \
    *reinterpret_cast<half8*>(&fragL[CUR ^ 1][wb0]) = l0;                      \
    *reinterpret_cast<half8*>(&fragL[CUR ^ 1][wb1]) = l1;                      \
    inv_scale = inv_n;                                                         \
    __syncthreads();                                                           \
  }

#pragma unroll 1
  for (int t = 0; t < TT; t += 2) {
    STEP(t, 0, eA0, eA1, eA2, eA3, eB0, eB1, eB2, eB3)
    STEP(t + 1, 1, eB0, eB1, eB2, eB3, eA0, eA1, eA2, eA3)
  }
#undef STEP

  // Epilogue: epg output = neurons [0,64) -> wave 0
  if (w == 0) {
#pragma unroll
    for (int nt = 0; nt < 4; ++nt) {
      f32x4 o;
#pragma unroll
      for (int q = 0; q < 4; ++q) o[q] = s_r[nt][q];
      *reinterpret_cast<f32x4*>(out + (size_t)br * 64 + nt * 16 + g * 4) = o;
    }
  }
}

extern "C" void kernel_launch(void* const* d_in, const int* in_sizes, int n_in,
                              void* d_out, int out_size, void* d_ws, size_t ws_size,
                              hipStream_t stream) {
  const float* W         = (const float*)d_in[0];
  const float* log_scale = (const float*)d_in[1];
  const float* gain      = (const float*)d_in[2];
  const float* bias      = (const float*)d_in[3];
  const float* log_tau   = (const float*)d_in[4];
  const float* vscale    = (const float*)d_in[5];
  const float* lscale    = (const float*)d_in[6];
  const float* velocity  = (const float*)d_in[7];
  const float* landmarks = (const float*)d_in[8];
  float* out = (float*)d_out;

  ring_attractor_kernel<<<dim3(BB / 16), dim3(256), 0, stream>>>(
      W, log_scale, gain, bias, log_tau, vscale, lscale, velocity, landmarks, out);
}

// Round 5
// 684.350 us; speedup vs baseline: 1.5028x; 1.0110x over previous
//
#include <hip/hip_runtime.h>

#define NN 256
#define TT 512
#define BB 1024
#define DTC 0.01f

typedef _Float16 half8 __attribute__((ext_vector_type(8)));
typedef float f32x4 __attribute__((ext_vector_type(4)));

// MFMA with A pinned in AGPRs (W resident for the whole kernel).
__device__ __forceinline__ f32x4 mfma_z(half8 a, half8 b) {
  f32x4 d;
  asm("v_mfma_f32_16x16x32_f16 %0, %1, %2, 0" : "=v"(d) : "a"(a), "v"(b));
  return d;
}
__device__ __forceinline__ void mfma_p(f32x4& c, half8 a, half8 b) {
  asm("v_mfma_f32_16x16x32_f16 %0, %1, %2, %0" : "+v"(c) : "a"(a), "v"(b));
}

// max with lane rotated-by-CTRL within the 16-lane DPP row (VALU pipe, no LDS)
template <int CTRL>
__device__ __forceinline__ float rormax(float x) {
  int yi = __builtin_amdgcn_update_dpp(0, __float_as_int(x), CTRL, 0xf, 0xf, false);
  return fmaxf(x, __int_as_float(yi));
}

// One block = 16 batch rows, 4 waves, wave w owns neurons [64w,64w+64).
// GEMM transposed: D[m=neuron][n=batchrow] = W_eff^T * s^T, 3-term f16 hi/lo.
// W^T in 256 AGPRs. Per-step structure: MFMA-bound (96 MFMA/wave, ~1950
// cyc/SIMD); the elementwise/quantize tail is interleaved into the last
// k-step's MFMA shadow (in-order issue, separate MFMA/VALU pipes).
__global__ __launch_bounds__(256, 1) void ring_attractor_kernel(
    const float* __restrict__ W, const float* __restrict__ log_scale,
    const float* __restrict__ gain, const float* __restrict__ bias,
    const float* __restrict__ log_tau, const float* __restrict__ vscale_p,
    const float* __restrict__ lscale_p, const float* __restrict__ velocity,
    const float* __restrict__ landmarks, float* __restrict__ out) {
  __shared__ __align__(16) _Float16 fragH[2][4096];
  __shared__ __align__(16) _Float16 fragL[2][4096];
  __shared__ __align__(16) float maxslot[2][4];

  const int tid = threadIdx.x;
  const int w  = tid >> 6;   // 0..3
  const int l  = tid & 63;
  const int g  = l >> 4;
  const int li = l & 15;
  const int br = blockIdx.x * 16 + li;

  const float es  = expf(log_scale[0]);
  const float vs  = vscale_p[0];
  const float lms = lscale_p[0];

  float gain_r[4][4], bias_r[4][4], coef_r[4][4];
#pragma unroll
  for (int nt = 0; nt < 4; ++nt)
#pragma unroll
    for (int q = 0; q < 4; ++q) {
      int c = w * 64 + nt * 16 + g * 4 + q;
      gain_r[nt][q] = gain[c];
      bias_r[nt][q] = bias[c];
      coef_r[nt][q] = DTC / expf(log_tau[c]);
    }

  // Resident W_eff^T hi/lo. A[m][k]: m = w*64+nt*16+li, k = 32ks+4g+(j&3)+16(j>>2)
  half8 whi[4][8], wlo[4][8];
#pragma unroll
  for (int nt = 0; nt < 4; ++nt)
#pragma unroll
    for (int ks = 0; ks < 8; ++ks) {
      half8 hi, lo;
#pragma unroll
      for (int j = 0; j < 8; ++j) {
        int k = ks * 32 + g * 4 + (j & 3) + ((j >> 2) << 4);
        int m = w * 64 + nt * 16 + li;
        float wv = W[k * NN + m] * es;
        _Float16 h = (_Float16)wv;
        hi[j] = h;
        lo[j] = (_Float16)(wv - (float)h);
      }
      whi[nt][ks] = hi;
      wlo[nt][ks] = lo;
    }

  float s_r[4][4];
#pragma unroll
  for (int nt = 0; nt < 4; ++nt)
#pragma unroll
    for (int q = 0; q < 4; ++q) s_r[nt][q] = 0.f;

  // Each lane owns 2 frag slots per buffer (k-slices ks = 2w, 2w+1)
  const int wb0 = ((w * 2 + 0) * 64 + g * 16 + li) * 8;
  const int wb1 = ((w * 2 + 1) * 64 + g * 16 + li) * 8;
  {
    half8 z;
#pragma unroll
    for (int j = 0; j < 8; ++j) z[j] = (_Float16)0.f;
    *reinterpret_cast<half8*>(&fragH[0][wb0]) = z;
    *reinterpret_cast<half8*>(&fragH[0][wb1]) = z;
    *reinterpret_cast<half8*>(&fragL[0][wb0]) = z;
    *reinterpret_cast<half8*>(&fragL[0][wb1]) = z;
    if (tid < 8) maxslot[tid >> 2][tid & 3] = 0.f;
  }
  float inv_scale = 1.f;
  float amPrev = 0.f;

  // Ext double-buffer: wave0 = 16 landmark floats; wave1 = v0,v1 in E0[0],E0[1]
  f32x4 eA0{}, eA1{}, eA2{}, eA3{}, eB0{}, eB1{}, eB2{}, eB3{};
  if (w == 0) {
    const float* p = landmarks + (size_t)br * 64 + g * 4;
    eA0 = *reinterpret_cast<const f32x4*>(p);
    eA1 = *reinterpret_cast<const f32x4*>(p + 16);
    eA2 = *reinterpret_cast<const f32x4*>(p + 32);
    eA3 = *reinterpret_cast<const f32x4*>(p + 48);
  } else if (w == 1) {
    const float* p = velocity + (size_t)br * 2;
    eA0[0] = p[0];
    eA0[1] = p[1];
  }
  __syncthreads();

// Per-tile elementwise tail: consume accs of tile NT, update s_r[NT][*], am.
#define TAIL(NT, AH, AL, AC, E0, E1, E2, E3)                                   \
  {                                                                            \
    f32x4 av = (AH + AL) + AC;                                                 \
    _Pragma("unroll")                                                          \
    for (int q = 0; q < 4; ++q) {                                              \
      float ext;                                                               \
      if (w == 0) {                                                            \
        f32x4 ev = (NT == 0) ? E0 : (NT == 1) ? E1 : (NT == 2) ? E2 : E3;      \
        ext = lms * ev[q];                                                     \
      } else if (w == 1) {                                                     \
        ext = vs * ((NT < 2) ? E0[0] : E0[1]);                                 \
      } else {                                                                 \
        ext = 0.f;                                                             \
      }                                                                        \
      float tot = __builtin_fmaf(av[q], inv_scale, ext);                       \
      float rate = fmaxf(__builtin_fmaf(gain_r[NT][q], tot, bias_r[NT][q]),    \
                         0.f);                                                 \
      float sv = s_r[NT][q];                                                   \
      sv = __builtin_fmaf(coef_r[NT][q], rate - sv, sv);                       \
      s_r[NT][q] = sv;                                                         \
      am = fmaxf(am, fabsf(sv));                                               \
    }                                                                          \
  }

#define STEP(T, CUR, E0, E1, E2, E3, P0, P1, P2, P3)                           \
  {                                                                            \
    /* (1) reduce prev step's per-lane max -> maxslot[CUR] (off crit path) */  \
    {                                                                          \
      float r = amPrev;                                                        \
      r = rormax<0x121>(r);                                                    \
      r = rormax<0x122>(r);                                                    \
      r = rormax<0x124>(r);                                                    \
      r = rormax<0x128>(r);                                                    \
      r = fmaxf(r, __shfl_xor(r, 16));                                         \
      r = fmaxf(r, __shfl_xor(r, 32));                                         \
      if (l == 0) maxslot[CUR][w] = r;                                         \
    }                                                                          \
    /* (2) M_{T-1} -> scale for s_{T+1} (branch-free, target max 2^7) */       \
    float scale_n, inv_n;                                                      \
    {                                                                          \
      f32x4 mv = *reinterpret_cast<const f32x4*>(&maxslot[CUR ^ 1][0]);        \
      float M = fmaxf(fmaxf(mv[0], mv[1]), fmaxf(mv[2], mv[3]));               \
      int e = 134 - (int)(__float_as_uint(M) >> 23);                           \
      e = e > 9 ? 9 : e;                                                       \
      scale_n = __int_as_float((e + 127) << 23);                               \
      inv_n = __int_as_float((127 - e) << 23);                                 \
    }                                                                          \
    /* (3) prefetch ext inputs for step T+1 */                                 \
    {                                                                          \
      const int tn = (T) + 1 < TT ? (T) + 1 : TT - 1;                          \
      if (w == 0) {                                                            \
        const float* p = landmarks + ((size_t)tn * BB + br) * 64 + g * 4;      \
        P0 = *reinterpret_cast<const f32x4*>(p);                               \
        P1 = *reinterpret_cast<const f32x4*>(p + 16);                          \
        P2 = *reinterpret_cast<const f32x4*>(p + 32);                          \
        P3 = *reinterpret_cast<const f32x4*>(p + 48);                          \
      } else if (w == 1) {                                                     \
        const float* p = velocity + ((size_t)tn * BB + br) * 2;                \
        P0[0] = p[0];                                                          \
        P0[1] = p[1];                                                          \
      }                                                                        \
    }                                                                          \
    /* (4) all 16 frag reads upfront; lgkmcnt pipelines them under MFMA */     \
    half8 bhr[8], blr[8];                                                      \
    _Pragma("unroll")                                                          \
    for (int ks = 0; ks < 8; ++ks) {                                           \
      const int rb = (ks * 64 + g * 16 + li) * 8;                              \
      bhr[ks] = *reinterpret_cast<const half8*>(&fragH[CUR][rb]);              \
      blr[ks] = *reinterpret_cast<const half8*>(&fragL[CUR][rb]);              \
    }                                                                          \
    /* (5) MFMA phase, ks 0..6 (12 chains, reuse distance 12) */               \
    f32x4 a0h, a1h, a2h, a3h, a0l, a1l, a2l, a3l, a0c, a1c, a2c, a3c;          \
    a0h = mfma_z(whi[0][0], bhr[0]);                                           \
    a1h = mfma_z(whi[1][0], bhr[0]);                                           \
    a2h = mfma_z(whi[2][0], bhr[0]);                                           \
    a3h = mfma_z(whi[3][0], bhr[0]);                                           \
    a0l = mfma_z(wlo[0][0], bhr[0]);                                           \
    a1l = mfma_z(wlo[1][0], bhr[0]);                                           \
    a2l = mfma_z(wlo[2][0], bhr[0]);                                           \
    a3l = mfma_z(wlo[3][0], bhr[0]);                                           \
    a0c = mfma_z(whi[0][0], blr[0]);                                           \
    a1c = mfma_z(whi[1][0], blr[0]);                                           \
    a2c = mfma_z(whi[2][0], blr[0]);                                           \
    a3c = mfma_z(whi[3][0], blr[0]);                                           \
    _Pragma("unroll")                                                          \
    for (int ks = 1; ks < 7; ++ks) {                                           \
      mfma_p(a0h, whi[0][ks], bhr[ks]);                                        \
      mfma_p(a1h, whi[1][ks], bhr[ks]);                                        \
      mfma_p(a2h, whi[2][ks], bhr[ks]);                                        \
      mfma_p(a3h, whi[3][ks], bhr[ks]);                                        \
      mfma_p(a0l, wlo[0][ks], bhr[ks]);                                        \
      mfma_p(a1l, wlo[1][ks], bhr[ks]);                                        \
      mfma_p(a2l, wlo[2][ks], bhr[ks]);                                        \
      mfma_p(a3l, wlo[3][ks], bhr[ks]);                                        \
      mfma_p(a0c, whi[0][ks], blr[ks]);                                        \
      mfma_p(a1c, whi[1][ks], blr[ks]);                                        \
      mfma_p(a2c, whi[2][ks], blr[ks]);                                        \
      mfma_p(a3c, whi[3][ks], blr[ks]);                                        \
    }                                                                          \
    /* (6) ks=7 per-tile + tails interleaved into the MFMA shadow */           \
    float am = 0.f;                                                            \
    mfma_p(a0h, whi[0][7], bhr[7]);                                            \
    mfma_p(a0l, wlo[0][7], bhr[7]);                                            \
    mfma_p(a0c, whi[0][7], blr[7]);                                            \
    mfma_p(a1h, whi[1][7], bhr[7]);                                            \
    mfma_p(a1l, wlo[1][7], bhr[7]);                                            \
    mfma_p(a1c, whi[1][7], blr[7]);                                            \
    asm volatile("s_nop 7" : "+v"(a0h), "+v"(a0l), "+v"(a0c));                 \
    TAIL(0, a0h, a0l, a0c, E0, E1, E2, E3)                                     \
    mfma_p(a2h, whi[2][7], bhr[7]);                                            \
    mfma_p(a2l, wlo[2][7], bhr[7]);                                            \
    mfma_p(a2c, whi[2][7], blr[7]);                                            \
    TAIL(1, a1h, a1l, a1c, E0, E1, E2, E3)                                     \
    mfma_p(a3h, whi[3][7], bhr[7]);                                            \
    mfma_p(a3l, wlo[3][7], bhr[7]);                                            \
    mfma_p(a3c, whi[3][7], blr[7]);                                            \
    /* quantize tiles 0,1 -> frag slot wb0 (hides under a2/a3 MFMAs) */        \
    {                                                                          \
      half8 h0, l0;                                                            \
      _Pragma("unroll")                                                        \
      for (int j = 0; j < 8; ++j) {                                            \
        float sc0 = s_r[j >> 2][j & 3] * scale_n;                              \
        _Float16 q0 = (_Float16)sc0;                                           \
        h0[j] = q0;                                                            \
        l0[j] = (_Float16)(sc0 - (float)q0);                                   \
      }                                                                        \
      *reinterpret_cast<half8*>(&fragH[CUR ^ 1][wb0]) = h0;                    \
      *reinterpret_cast<half8*>(&fragL[CUR ^ 1][wb0]) = l0;                    \
    }                                                                          \
    TAIL(2, a2h, a2l, a2c, E0, E1, E2, E3)                                     \
    asm volatile("s_nop 7" : "+v"(a3h), "+v"(a3l), "+v"(a3c));                 \
    TAIL(3, a3h, a3l, a3c, E0, E1, E2, E3)                                     \
    /* quantize tiles 2,3 -> frag slot wb1 */                                  \
    {                                                                          \
      half8 h1, l1;                                                            \
      _Pragma("unroll")                                                        \
      for (int j = 0; j < 8; ++j) {                                            \
        float sc1 = s_r[2 + (j >> 2)][j & 3] * scale_n;                        \
        _Float16 q1 = (_Float16)sc1;                                           \
        h1[j] = q1;                                                            \
        l1[j] = (_Float16)(sc1 - (float)q1);                                   \
      }                                                                        \
      *reinterpret_cast<half8*>(&fragH[CUR ^ 1][wb1]) = h1;                    \
      *reinterpret_cast<half8*>(&fragL[CUR ^ 1][wb1]) = l1;                    \
    }                                                                          \
    amPrev = am;                                                               \
    inv_scale = inv_n;                                                         \
    __syncthreads();                                                           \
  }

#pragma unroll 1
  for (int t = 0; t < TT; t += 2) {
    STEP(t, 0, eA0, eA1, eA2, eA3, eB0, eB1, eB2, eB3)
    STEP(t + 1, 1, eB0, eB1, eB2, eB3, eA0, eA1, eA2, eA3)
  }
#undef STEP
#undef TAIL

  // Epilogue: epg output = neurons [0,64) -> wave 0
  if (w == 0) {
#pragma unroll
    for (int nt = 0; nt < 4; ++nt) {
      f32x4 o;
#pragma unroll
      for (int q = 0; q < 4; ++q) o[q] = s_r[nt][q];
      *reinterpret_cast<f32x4*>(out + (size_t)br * 64 + nt * 16 + g * 4) = o;
    }
  }
}

extern "C" void kernel_launch(void* const* d_in, const int* in_sizes, int n_in,
                              void* d_out, int out_size, void* d_ws, size_t ws_size,
                              hipStream_t stream) {
  const float* W         = (const float*)d_in[0];
  const float* log_scale = (const float*)d_in[1];
  const float* gain      = (const float*)d_in[2];
  const float* bias      = (const float*)d_in[3];
  const float* log_tau   = (const float*)d_in[4];
  const float* vscale    = (const float*)d_in[5];
  const float* lscale    = (const float*)d_in[6];
  const float* velocity  = (const float*)d_in[7];
  const float* landmarks = (const float*)d_in[8];
  float* out = (float*)d_out;

  ring_attractor_kernel<<<dim3(BB / 16), dim3(256), 0, stream>>>(
      W, log_scale, gain, bias, log_tau, vscale, lscale, velocity, landmarks, out);
}